// Round 6
// baseline (953.007 us; speedup 1.0000x reference)
//
#include <hip/hip_runtime.h>
#include <hip/hip_bf16.h>
#include <math.h>

#define C_DIM 1024
#define N_DIM 3072   // 3*C
#define QKS  2048    // Q|K row stride in bf16 workspace

typedef __attribute__((ext_vector_type(8))) short bf16x8;   // 8 bf16 = 4 VGPRs
typedef __attribute__((ext_vector_type(4))) float f32x4;    // MFMA C/D

__device__ __forceinline__ unsigned short f2bf(float f) {
  __hip_bfloat16 h = __float2bfloat16(f);
  return *(reinterpret_cast<unsigned short*>(&h));
}
__device__ __forceinline__ float bf2f(unsigned short u) {
  return __uint_as_float(((unsigned int)u) << 16);
}
__device__ __forceinline__ f32x4 mfma16(bf16x8 a, bf16x8 b, f32x4 c) {
  return __builtin_amdgcn_mfma_f32_16x16x32_bf16(a, b, c, 0, 0, 0);
}

// ---------------------------------------------------------------------------
// Kernel 1: qkv = x @ W + b (fp32 compute).  Q,K -> row-major bf16 [T][2048];
// V -> TRANSPOSED bf16 [1024][T] so PV B-fragments are contiguous.
// ---------------------------------------------------------------------------
#define GT 128
#define GK 16

__device__ __forceinline__ void fma44(float (&c)[4][4], const float4& a, const float4& b) {
  const float av[4] = {a.x, a.y, a.z, a.w};
  const float bv[4] = {b.x, b.y, b.z, b.w};
#pragma unroll
  for (int i = 0; i < 4; ++i)
#pragma unroll
    for (int j = 0; j < 4; ++j) c[i][j] += av[i] * bv[j];
}

__global__ __launch_bounds__(256) void qkv_gemm(
    const float* __restrict__ x, const float* __restrict__ W,
    const float* __restrict__ bias, unsigned short* __restrict__ qkb,
    unsigned short* __restrict__ vtb, int T) {
  __shared__ float As[GK][GT];
  __shared__ float Bs[GK][GT];
  const int tid  = threadIdx.x;
  const int row0 = blockIdx.y * GT;
  const int col0 = blockIdx.x * GT;
  const int tm = (tid >> 4) << 2;
  const int tn = (tid & 15) << 2;
  const int ar = tid >> 1;
  const int ac = (tid & 1) << 3;
  const int br = tid >> 4;
  const int bc = (tid & 15) << 3;

  float acc[2][2][4][4] = {};

  const float* xp = x + (size_t)(row0 + ar) * C_DIM + ac;
  const float* wp = W + (size_t)br * N_DIM + col0 + bc;

  for (int k0 = 0; k0 < C_DIM; k0 += GK) {
    float4 a0 = *(const float4*)(xp + k0);
    float4 a1 = *(const float4*)(xp + k0 + 4);
    float4 b0 = *(const float4*)(wp + (size_t)k0 * N_DIM);
    float4 b1 = *(const float4*)(wp + (size_t)k0 * N_DIM + 4);
    __syncthreads();
    As[ac + 0][ar] = a0.x; As[ac + 1][ar] = a0.y;
    As[ac + 2][ar] = a0.z; As[ac + 3][ar] = a0.w;
    As[ac + 4][ar] = a1.x; As[ac + 5][ar] = a1.y;
    As[ac + 6][ar] = a1.z; As[ac + 7][ar] = a1.w;
    *(float4*)&Bs[br][bc]     = b0;
    *(float4*)&Bs[br][bc + 4] = b1;
    __syncthreads();
#pragma unroll
    for (int k = 0; k < GK; ++k) {
      float4 aL = *(const float4*)&As[k][tm];
      float4 aH = *(const float4*)&As[k][tm + 64];
      float4 bL = *(const float4*)&Bs[k][tn];
      float4 bH = *(const float4*)&Bs[k][tn + 64];
      fma44(acc[0][0], aL, bL);
      fma44(acc[0][1], aL, bH);
      fma44(acc[1][0], aH, bL);
      fma44(acc[1][1], aH, bH);
    }
  }

  const bool isV = (col0 >= 2 * C_DIM);
#pragma unroll
  for (int qi = 0; qi < 2; ++qi) {
#pragma unroll
    for (int i = 0; i < 4; ++i) {
      const int row = row0 + qi * 64 + tm + i;
#pragma unroll
      for (int qj = 0; qj < 2; ++qj) {
        const int col = col0 + qj * 64 + tn;
        if (!isV) {
          ushort4 u;
          u.x = f2bf(acc[qi][qj][i][0] + bias[col + 0]);
          u.y = f2bf(acc[qi][qj][i][1] + bias[col + 1]);
          u.z = f2bf(acc[qi][qj][i][2] + bias[col + 2]);
          u.w = f2bf(acc[qi][qj][i][3] + bias[col + 3]);
          *(ushort4*)(qkb + (size_t)row * QKS + col) = u;
        } else {
#pragma unroll
          for (int c = 0; c < 4; ++c)
            vtb[(size_t)(col + c - 2 * C_DIM) * T + row] =
                f2bf(acc[qi][qj][i][c] + bias[col + c]);
        }
      }
    }
  }
}

// ---------------------------------------------------------------------------
// Kernel 2: flash attention, bf16 MFMA, BQ=32, BK=128, NO K/Q/V LDS staging.
// Q,K,V^T are in fragment-friendly layouts -> direct global b128 frag loads.
// Only P round-trips LDS (C-layout -> A-layout). 2 barriers per chunk.
// ---------------------------------------------------------------------------
__global__ __launch_bounds__(256) void attn_mfma(
    const unsigned short* __restrict__ qkb, const unsigned short* __restrict__ vtb,
    const int* __restrict__ np_p, float* __restrict__ out, float* __restrict__ part,
    float2* __restrict__ ml, int T, int nblocks) {
  __shared__ __align__(16) unsigned short Ps[32][136];   // [row][key] 8.7 KB
  __shared__ float mw[4][32];
  __shared__ float lw[4][32];

  const int tid  = threadIdx.x;
  const int lane = tid & 63;
  const int w    = tid >> 6;
  const int qd   = lane >> 4;    // quad
  const int n16  = lane & 15;

  // block -> (tile, seg); reversed so biggest blocks dispatch first
  int rb = (nblocks - 1) - (int)blockIdx.x;
  int g = 0;
  while (rb >= 32 * (g + 1)) { rb -= 32 * (g + 1); ++g; }
  const int tile = g * 32 + (rb & 31);
  const int seg  = rb >> 5;
  const int nseg = g + 1;
  const int row0 = tile * 32;
  const int kmax = row0 + 32;
  const int nch  = (kmax + 127) >> 7;
  const int cbase = nch / nseg, cext = nch % nseg;
  const int ch0 = seg * cbase + (seg < cext ? seg : cext);
  const int ch1 = ch0 + cbase + (seg < cext ? 1 : 0);
  const int np = *np_p;

  f32x4 o[16][2];                 // [col-slice][row-tile]
#pragma unroll
  for (int cs = 0; cs < 16; ++cs)
#pragma unroll
    for (int rt = 0; rt < 2; ++rt) o[cs][rt] = (f32x4){0.f, 0.f, 0.f, 0.f};
  float m_i[2][4], l_i[2][4];
#pragma unroll
  for (int rt = 0; rt < 2; ++rt)
#pragma unroll
    for (int r = 0; r < 4; ++r) { m_i[rt][r] = -3.0e38f; l_i[rt][r] = 0.f; }

  const unsigned short* qrow0 = qkb + (size_t)(row0 + n16) * QKS + (qd << 3);
  const unsigned short* qrow1 = qkb + (size_t)(row0 + 16 + n16) * QKS + (qd << 3);

  for (int ch = ch0; ch < ch1; ++ch) {
    const int kc0 = ch << 7;
    f32x4 s[2][2];
#pragma unroll
    for (int rt = 0; rt < 2; ++rt)
#pragma unroll
      for (int kt = 0; kt < 2; ++kt) s[rt][kt] = (f32x4){0.f, 0.f, 0.f, 0.f};

    // ---- S = Q K^T : direct global fragment loads, no LDS, no barriers
    const unsigned short* krow0 =
        qkb + (size_t)(kc0 + (w << 5) + n16) * QKS + C_DIM + (qd << 3);
    const unsigned short* krow1 = krow0 + (size_t)16 * QKS;
#pragma unroll 4
    for (int ks = 0; ks < C_DIM; ks += 32) {
      bf16x8 a0 = *(const bf16x8*)(qrow0 + ks);
      bf16x8 a1 = *(const bf16x8*)(qrow1 + ks);
      bf16x8 b0 = *(const bf16x8*)(krow0 + ks);
      bf16x8 b1 = *(const bf16x8*)(krow1 + ks);
      s[0][0] = mfma16(a0, b0, s[0][0]);
      s[0][1] = mfma16(a0, b1, s[0][1]);
      s[1][0] = mfma16(a1, b0, s[1][0]);
      s[1][1] = mfma16(a1, b1, s[1][1]);
    }

    // ---- online softmax (16-lane reduce + cross-wave LDS combine)
    float al[2][4];
#pragma unroll
    for (int rt = 0; rt < 2; ++rt) {
#pragma unroll
      for (int r = 0; r < 4; ++r) {
        const int rowg = row0 + (rt << 4) + (qd << 2) + r;
        const int j0 = kc0 + (w << 5) + n16;
        const int j1 = j0 + 16;
        float sv0 = ((j0 <= rowg) && (j0 >= np)) ? s[rt][0][r] * 0.03125f : -3.0e38f;
        float sv1 = ((j1 <= rowg) && (j1 >= np)) ? s[rt][1][r] * 0.03125f : -3.0e38f;
        s[rt][0][r] = sv0; s[rt][1][r] = sv1;
        float m2 = fmaxf(sv0, sv1);
        m2 = fmaxf(m2, __shfl_xor(m2, 1));
        m2 = fmaxf(m2, __shfl_xor(m2, 2));
        m2 = fmaxf(m2, __shfl_xor(m2, 4));
        m2 = fmaxf(m2, __shfl_xor(m2, 8));
        if (n16 == r) mw[w][(rt << 4) + (qd << 2) + r] = m2;
      }
    }
    __syncthreads();
#pragma unroll
    for (int rt = 0; rt < 2; ++rt) {
#pragma unroll
      for (int r = 0; r < 4; ++r) {
        const int row = (rt << 4) + (qd << 2) + r;
        float mn = fmaxf(fmaxf(mw[0][row], mw[1][row]), fmaxf(mw[2][row], mw[3][row]));
        mn = fmaxf(mn, m_i[rt][r]);
        al[rt][r] = __expf(m_i[rt][r] - mn);
        m_i[rt][r] = mn;
        float p0 = (s[rt][0][r] > -1.0e30f) ? __expf(s[rt][0][r] - mn) : 0.f;
        float p1 = (s[rt][1][r] > -1.0e30f) ? __expf(s[rt][1][r] - mn) : 0.f;
        Ps[row][(w << 5) + n16]      = f2bf(p0);
        Ps[row][(w << 5) + 16 + n16] = f2bf(p1);
        float ls = p0 + p1;
        ls += __shfl_xor(ls, 1);
        ls += __shfl_xor(ls, 2);
        ls += __shfl_xor(ls, 4);
        ls += __shfl_xor(ls, 8);
        if (n16 == r) lw[w][row] = ls;
      }
    }
    __syncthreads();
#pragma unroll
    for (int rt = 0; rt < 2; ++rt)
#pragma unroll
      for (int r = 0; r < 4; ++r) {
        const int row = (rt << 4) + (qd << 2) + r;
        l_i[rt][r] = l_i[rt][r] * al[rt][r] +
                     (lw[0][row] + lw[1][row] + lw[2][row] + lw[3][row]);
      }
#pragma unroll
    for (int cs = 0; cs < 16; ++cs)
#pragma unroll
      for (int rt = 0; rt < 2; ++rt) {
        o[cs][rt][0] *= al[rt][0];
        o[cs][rt][1] *= al[rt][1];
        o[cs][rt][2] *= al[rt][2];
        o[cs][rt][3] *= al[rt][3];
      }

    // ---- O += P V : P-frags from LDS once, V^T frags direct from global
    bf16x8 pa[2][4];
#pragma unroll
    for (int kb = 0; kb < 4; ++kb) {
      const int kk = (kb << 5) + (qd << 3);
      pa[0][kb] = *(const bf16x8*)&Ps[n16][kk];
      pa[1][kb] = *(const bf16x8*)&Ps[16 + n16][kk];
    }
    const unsigned short* vtp0 =
        vtb + (size_t)((w << 4) + n16) * T + kc0 + (qd << 3);
#pragma unroll 2
    for (int cs = 0; cs < 16; ++cs) {
      const unsigned short* vtp = vtp0 + (size_t)(cs << 6) * T;
#pragma unroll
      for (int kb = 0; kb < 4; ++kb) {
        bf16x8 vb = *(const bf16x8*)(vtp + (kb << 5));
        o[cs][0] = mfma16(pa[0][kb], vb, o[cs][0]);
        o[cs][1] = mfma16(pa[1][kb], vb, o[cs][1]);
      }
    }
  }

  // ---- epilogue: unnormalized O + (m,l)
  float* dst;
  int radj;
  if (seg == 0) { dst = out; radj = 0; }
  else {
    dst = part + ((size_t)(seg - 1) * T - (size_t)(seg * (seg - 1) / 2) * 1024) * C_DIM;
    radj = seg << 10;
  }
#pragma unroll
  for (int cs = 0; cs < 16; ++cs)
#pragma unroll
    for (int rt = 0; rt < 2; ++rt)
#pragma unroll
      for (int r = 0; r < 4; ++r) {
        const int row = row0 + (rt << 4) + (qd << 2) + r;
        const int col = (cs << 6) + (w << 4) + n16;
        dst[(size_t)(row - radj) * C_DIM + col] = o[cs][rt][r];
      }
  if (w == 0 && n16 == 0) {
#pragma unroll
    for (int rt = 0; rt < 2; ++rt)
#pragma unroll
      for (int r = 0; r < 4; ++r) {
        const int row = row0 + (rt << 4) + (qd << 2) + r;
        ml[(size_t)seg * T + row] = make_float2(m_i[rt][r], l_i[rt][r]);
      }
  }

  // ---- padded rows (< n_padd): uniform over ALL T keys (from V^T rows)
  if (seg == 0 && np > row0) {
    const int pc = min(np - row0, 32);
    const int c4 = tid << 2;
    float a[4] = {0.f, 0.f, 0.f, 0.f};
#pragma unroll
    for (int c = 0; c < 4; ++c) {
      const unsigned short* vr = vtb + (size_t)(c4 + c) * T;
      for (int j = 0; j < T; j += 8) {
        uint4 v = *(const uint4*)(vr + j);
        a[c] += bf2f(v.x & 0xffff) + bf2f(v.x >> 16) + bf2f(v.y & 0xffff) + bf2f(v.y >> 16)
              + bf2f(v.z & 0xffff) + bf2f(v.z >> 16) + bf2f(v.w & 0xffff) + bf2f(v.w >> 16);
      }
    }
    const float inv = 1.0f / (float)T;
    float4 rv = {a[0] * inv, a[1] * inv, a[2] * inv, a[3] * inv};
    for (int r = 0; r < pc; ++r)
      *(float4*)(out + (size_t)(row0 + r) * C_DIM + c4) = rv;
  }
}

// ---------------------------------------------------------------------------
// Kernel 3: merge up to 4 segments per row
// ---------------------------------------------------------------------------
__global__ __launch_bounds__(256) void attn_merge4(
    float* __restrict__ out, const float* __restrict__ part,
    const float2* __restrict__ ml, const int* __restrict__ np_p, int T) {
  const int row = blockIdx.x;
  if (row < *np_p) return;
  const int ns = (row >> 10) + 1;
  const int c = threadIdx.x << 2;
  float2 m0 = ml[row];
  if (ns == 1) {
    const float inv = 1.0f / m0.y;
    float4 o0 = *(const float4*)(out + (size_t)row * C_DIM + c);
    o0.x *= inv; o0.y *= inv; o0.z *= inv; o0.w *= inv;
    *(float4*)(out + (size_t)row * C_DIM + c) = o0;
    return;
  }
  float2 ms[3];
  float M = m0.x;
  for (int s = 1; s < ns; ++s) { ms[s-1] = ml[(size_t)s * T + row]; M = fmaxf(M, ms[s-1].x); }
  const float w0 = __expf(m0.x - M);
  float L = w0 * m0.y;
  float ws[3];
  for (int s = 1; s < ns; ++s) { ws[s-1] = __expf(ms[s-1].x - M); L += ws[s-1] * ms[s-1].y; }
  const float inv = 1.0f / L;
  float4 acc = *(const float4*)(out + (size_t)row * C_DIM + c);
  acc.x *= w0; acc.y *= w0; acc.z *= w0; acc.w *= w0;
  for (int s = 1; s < ns; ++s) {
    const float* pp = part + ((size_t)(s - 1) * T - (size_t)(s * (s - 1) / 2) * 1024) * C_DIM
                    + (size_t)(row - (s << 10)) * C_DIM + c;
    float4 p = *(const float4*)pp;
    acc.x += ws[s-1] * p.x; acc.y += ws[s-1] * p.y;
    acc.z += ws[s-1] * p.z; acc.w += ws[s-1] * p.w;
  }
  acc.x *= inv; acc.y *= inv; acc.z *= inv; acc.w *= inv;
  *(float4*)(out + (size_t)row * C_DIM + c) = acc;
}

// ---------------------------------------------------------------------------
extern "C" void kernel_launch(void* const* d_in, const int* in_sizes, int n_in,
                              void* d_out, int out_size, void* d_ws, size_t ws_size,
                              hipStream_t stream) {
  const float* x    = (const float*)d_in[0];
  const float* W    = (const float*)d_in[1];
  const float* b    = (const float*)d_in[2];
  const int* n_padd = (const int*)d_in[3];
  float* out = (float*)d_out;

  const int T = in_sizes[0] / C_DIM;
  unsigned short* qkb = (unsigned short*)d_ws;                    // [T][2048] bf16 = 16 MB
  unsigned short* vtb = qkb + (size_t)T * QKS;                    // [1024][T] bf16 =  8 MB
  float* part = (float*)(vtb + (size_t)C_DIM * T);                // (3T-6144)*1024 fp32 ~25 MB
  float2* ml  = (float2*)(part + (size_t)(3 * T - 6144) * C_DIM); // 4*T float2

  dim3 g1(N_DIM / GT, (T + GT - 1) / GT);
  qkv_gemm<<<g1, 256, 0, stream>>>(x, W, b, qkb, vtb, T);

  const int ntiles = T / 32;
  int nblk = 0;
  for (int t = 0; t < ntiles; ++t) nblk += t / 32 + 1;
  attn_mfma<<<nblk, 256, 0, stream>>>(qkb, vtb, n_padd, out, part, ml, T, nblk);

  attn_merge4<<<T, 256, 0, stream>>>(out, part, ml, n_padd, T);
}

// Round 7
// 721.630 us; speedup vs baseline: 1.3206x; 1.3206x over previous
//
#include <hip/hip_runtime.h>
#include <hip/hip_bf16.h>
#include <math.h>

#define C_DIM 1024
#define QKS  2048    // Q|K row stride in bf16 workspace

typedef __attribute__((ext_vector_type(8))) short bf16x8;   // 8 bf16 = 4 VGPRs
typedef __attribute__((ext_vector_type(4))) float f32x4;    // MFMA C/D

__device__ __forceinline__ unsigned short f2bf(float f) {
  __hip_bfloat16 h = __float2bfloat16(f);
  return *(reinterpret_cast<unsigned short*>(&h));
}
__device__ __forceinline__ float bf2f(unsigned short u) {
  return __uint_as_float(((unsigned int)u) << 16);
}
__device__ __forceinline__ f32x4 mfma16(bf16x8 a, bf16x8 b, f32x4 c) {
  return __builtin_amdgcn_mfma_f32_16x16x32_bf16(a, b, c, 0, 0, 0);
}

// ---------------------------------------------------------------------------
// Kernel 0a: cast x (fp32) -> xb (bf16), elementwise
// ---------------------------------------------------------------------------
__global__ __launch_bounds__(256) void cast_x(
    const float* __restrict__ x, unsigned short* __restrict__ xb) {
  const int i = (blockIdx.x * 256 + threadIdx.x) << 2;
  float4 v = *(const float4*)(x + i);
  ushort4 u;
  u.x = f2bf(v.x); u.y = f2bf(v.y); u.z = f2bf(v.z); u.w = f2bf(v.w);
  *(ushort4*)(xb + i) = u;
}

// ---------------------------------------------------------------------------
// Kernel 0b: W [1024][3072] fp32 -> WT [3072][1024] bf16 (LDS 64x64 tiles)
// ---------------------------------------------------------------------------
__global__ __launch_bounds__(256) void transpose_w(
    const float* __restrict__ W, unsigned short* __restrict__ WT) {
  __shared__ float Ls[64][65];
  const int n0 = blockIdx.x * 64;   // W col block = WT row block
  const int k0 = blockIdx.y * 64;   // W row block = WT col block
  const int c = (threadIdx.x & 15) << 2;
  const int r = threadIdx.x >> 4;
#pragma unroll
  for (int rr = 0; rr < 64; rr += 16) {
    float4 v = *(const float4*)(W + (size_t)(k0 + r + rr) * 3072 + n0 + c);
    Ls[r + rr][c + 0] = v.x; Ls[r + rr][c + 1] = v.y;
    Ls[r + rr][c + 2] = v.z; Ls[r + rr][c + 3] = v.w;
  }
  __syncthreads();
#pragma unroll
  for (int rr = 0; rr < 64; rr += 16) {
    const int X = r + rr;
    ushort4 u;
    u.x = f2bf(Ls[c + 0][X]); u.y = f2bf(Ls[c + 1][X]);
    u.z = f2bf(Ls[c + 2][X]); u.w = f2bf(Ls[c + 3][X]);
    *(ushort4*)(WT + (size_t)(n0 + X) * C_DIM + k0 + c) = u;
  }
}

// ---------------------------------------------------------------------------
// Kernel 1: C = A @ BT^T + bias, bf16 MFMA, direct fragment loads (no LDS).
// A [M][1024] bf16 row-major, BT [N][1024] bf16 row-major (k-contiguous).
// Block = 128x128 tile, 256 thr; wave w -> cols [w*32, w*32+32), 8 m-tiles.
// bias_row=0: bias[col] (Q|K). bias_row=1: bias[row] (V^T form).
// ---------------------------------------------------------------------------
__global__ __launch_bounds__(256) void gemm_bt(
    const unsigned short* __restrict__ A, const unsigned short* __restrict__ BT,
    unsigned short* __restrict__ C, const float* __restrict__ bias,
    int ldc, int bias_row) {
  const int tid = threadIdx.x, lane = tid & 63, w = tid >> 6;
  const int qd = lane >> 4, n16 = lane & 15;
  const int m0 = blockIdx.y * 128;
  const int n0 = blockIdx.x * 128 + (w << 5);

  f32x4 s[8][2];
#pragma unroll
  for (int mt = 0; mt < 8; ++mt)
#pragma unroll
    for (int j = 0; j < 2; ++j) s[mt][j] = (f32x4){0.f, 0.f, 0.f, 0.f};

  const unsigned short* ap = A + (size_t)(m0 + n16) * C_DIM + (qd << 3);
  const unsigned short* bp = BT + (size_t)(n0 + n16) * C_DIM + (qd << 3);

#pragma unroll 2
  for (int ks = 0; ks < C_DIM; ks += 32) {
    bf16x8 b0 = *(const bf16x8*)(bp + ks);
    bf16x8 b1 = *(const bf16x8*)(bp + (size_t)16 * C_DIM + ks);
#pragma unroll
    for (int mt = 0; mt < 8; ++mt) {
      bf16x8 a = *(const bf16x8*)(ap + (size_t)(mt << 4) * C_DIM + ks);
      s[mt][0] = mfma16(a, b0, s[mt][0]);
      s[mt][1] = mfma16(a, b1, s[mt][1]);
    }
  }

#pragma unroll
  for (int mt = 0; mt < 8; ++mt)
#pragma unroll
    for (int j = 0; j < 2; ++j) {
      const int col = n0 + (j << 4) + n16;
      const float bc = bias_row ? 0.f : bias[col];
#pragma unroll
      for (int r = 0; r < 4; ++r) {
        const int row = m0 + (mt << 4) + (qd << 2) + r;
        const float bv = bias_row ? bias[row] : bc;
        C[(size_t)row * ldc + col] = f2bf(s[mt][j][r] + bv);
      }
    }
}

// ---------------------------------------------------------------------------
// Kernel 2: flash attention, bf16 MFMA, BQ=32, BK=128, direct global frags.
// DESPILLED: every loop touching o[][] is fully unrolled (static indices) so
// the O accumulator stays in AGPRs/VGPRs instead of scratch (R5/R6 bug).
// ---------------------------------------------------------------------------
__global__ __launch_bounds__(256) void attn_mfma(
    const unsigned short* __restrict__ qkb, const unsigned short* __restrict__ vtb,
    const int* __restrict__ np_p, float* __restrict__ out, float* __restrict__ part,
    float2* __restrict__ ml, int T, int nblocks) {
  __shared__ __align__(16) unsigned short Ps[32][136];
  __shared__ float mw[4][32];
  __shared__ float lw[4][32];

  const int tid  = threadIdx.x;
  const int lane = tid & 63;
  const int w    = tid >> 6;
  const int qd   = lane >> 4;
  const int n16  = lane & 15;

  int rb = (nblocks - 1) - (int)blockIdx.x;
  int g = 0;
  while (rb >= 32 * (g + 1)) { rb -= 32 * (g + 1); ++g; }
  const int tile = g * 32 + (rb & 31);
  const int seg  = rb >> 5;
  const int nseg = g + 1;
  const int row0 = tile * 32;
  const int kmax = row0 + 32;
  const int nch  = (kmax + 127) >> 7;
  const int cbase = nch / nseg, cext = nch % nseg;
  const int ch0 = seg * cbase + (seg < cext ? seg : cext);
  const int ch1 = ch0 + cbase + (seg < cext ? 1 : 0);
  const int np = *np_p;

  f32x4 o[16][2];
#pragma unroll
  for (int cs = 0; cs < 16; ++cs)
#pragma unroll
    for (int rt = 0; rt < 2; ++rt) o[cs][rt] = (f32x4){0.f, 0.f, 0.f, 0.f};
  float m_i[2][4], l_i[2][4];
#pragma unroll
  for (int rt = 0; rt < 2; ++rt)
#pragma unroll
    for (int r = 0; r < 4; ++r) { m_i[rt][r] = -3.0e38f; l_i[rt][r] = 0.f; }

  const unsigned short* qrow0 = qkb + (size_t)(row0 + n16) * QKS + (qd << 3);
  const unsigned short* qrow1 = qkb + (size_t)(row0 + 16 + n16) * QKS + (qd << 3);

  for (int ch = ch0; ch < ch1; ++ch) {
    const int kc0 = ch << 7;
    f32x4 s[2][2];
#pragma unroll
    for (int rt = 0; rt < 2; ++rt)
#pragma unroll
      for (int kt = 0; kt < 2; ++kt) s[rt][kt] = (f32x4){0.f, 0.f, 0.f, 0.f};

    // ---- S = Q K^T : direct global fragment loads
    const unsigned short* krow0 =
        qkb + (size_t)(kc0 + (w << 5) + n16) * QKS + C_DIM + (qd << 3);
    const unsigned short* krow1 = krow0 + (size_t)16 * QKS;
#pragma unroll 4
    for (int ks = 0; ks < C_DIM; ks += 32) {
      bf16x8 a0 = *(const bf16x8*)(qrow0 + ks);
      bf16x8 a1 = *(const bf16x8*)(qrow1 + ks);
      bf16x8 b0 = *(const bf16x8*)(krow0 + ks);
      bf16x8 b1 = *(const bf16x8*)(krow1 + ks);
      s[0][0] = mfma16(a0, b0, s[0][0]);
      s[0][1] = mfma16(a0, b1, s[0][1]);
      s[1][0] = mfma16(a1, b0, s[1][0]);
      s[1][1] = mfma16(a1, b1, s[1][1]);
    }

    // ---- online softmax
    float al[2][4];
#pragma unroll
    for (int rt = 0; rt < 2; ++rt) {
#pragma unroll
      for (int r = 0; r < 4; ++r) {
        const int rowg = row0 + (rt << 4) + (qd << 2) + r;
        const int j0 = kc0 + (w << 5) + n16;
        const int j1 = j0 + 16;
        float sv0 = ((j0 <= rowg) && (j0 >= np)) ? s[rt][0][r] * 0.03125f : -3.0e38f;
        float sv1 = ((j1 <= rowg) && (j1 >= np)) ? s[rt][1][r] * 0.03125f : -3.0e38f;
        s[rt][0][r] = sv0; s[rt][1][r] = sv1;
        float m2 = fmaxf(sv0, sv1);
        m2 = fmaxf(m2, __shfl_xor(m2, 1));
        m2 = fmaxf(m2, __shfl_xor(m2, 2));
        m2 = fmaxf(m2, __shfl_xor(m2, 4));
        m2 = fmaxf(m2, __shfl_xor(m2, 8));
        if (n16 == r) mw[w][(rt << 4) + (qd << 2) + r] = m2;
      }
    }
    __syncthreads();
#pragma unroll
    for (int rt = 0; rt < 2; ++rt) {
#pragma unroll
      for (int r = 0; r < 4; ++r) {
        const int row = (rt << 4) + (qd << 2) + r;
        float mn = fmaxf(fmaxf(mw[0][row], mw[1][row]), fmaxf(mw[2][row], mw[3][row]));
        mn = fmaxf(mn, m_i[rt][r]);
        al[rt][r] = __expf(m_i[rt][r] - mn);
        m_i[rt][r] = mn;
        float p0 = (s[rt][0][r] > -1.0e30f) ? __expf(s[rt][0][r] - mn) : 0.f;
        float p1 = (s[rt][1][r] > -1.0e30f) ? __expf(s[rt][1][r] - mn) : 0.f;
        Ps[row][(w << 5) + n16]      = f2bf(p0);
        Ps[row][(w << 5) + 16 + n16] = f2bf(p1);
        float ls = p0 + p1;
        ls += __shfl_xor(ls, 1);
        ls += __shfl_xor(ls, 2);
        ls += __shfl_xor(ls, 4);
        ls += __shfl_xor(ls, 8);
        if (n16 == r) lw[w][row] = ls;
      }
    }
    __syncthreads();
#pragma unroll
    for (int rt = 0; rt < 2; ++rt)
#pragma unroll
      for (int r = 0; r < 4; ++r) {
        const int row = (rt << 4) + (qd << 2) + r;
        l_i[rt][r] = l_i[rt][r] * al[rt][r] +
                     (lw[0][row] + lw[1][row] + lw[2][row] + lw[3][row]);
      }
#pragma unroll
    for (int cs = 0; cs < 16; ++cs)
#pragma unroll
      for (int rt = 0; rt < 2; ++rt) {
        o[cs][rt][0] *= al[rt][0];
        o[cs][rt][1] *= al[rt][1];
        o[cs][rt][2] *= al[rt][2];
        o[cs][rt][3] *= al[rt][3];
      }

    // ---- O += P V : kb-outer / cs-inner, FULLY unrolled (no spill)
#pragma unroll
    for (int kb = 0; kb < 4; ++kb) {
      const int kk = (kb << 5) + (qd << 3);
      bf16x8 pa0 = *(const bf16x8*)&Ps[n16][kk];
      bf16x8 pa1 = *(const bf16x8*)&Ps[16 + n16][kk];
      const unsigned short* vtp =
          vtb + (size_t)((w << 4) + n16) * T + kc0 + (qd << 3) + (kb << 5);
#pragma unroll
      for (int cs = 0; cs < 16; ++cs) {
        bf16x8 vb = *(const bf16x8*)(vtp + (size_t)(cs << 6) * T);
        o[cs][0] = mfma16(pa0, vb, o[cs][0]);
        o[cs][1] = mfma16(pa1, vb, o[cs][1]);
      }
    }
  }

  // ---- epilogue: unnormalized O + (m,l)
  float* dst;
  int radj;
  if (seg == 0) { dst = out; radj = 0; }
  else {
    dst = part + ((size_t)(seg - 1) * T - (size_t)(seg * (seg - 1) / 2) * 1024) * C_DIM;
    radj = seg << 10;
  }
#pragma unroll
  for (int cs = 0; cs < 16; ++cs)
#pragma unroll
    for (int rt = 0; rt < 2; ++rt)
#pragma unroll
      for (int r = 0; r < 4; ++r) {
        const int row = row0 + (rt << 4) + (qd << 2) + r;
        const int col = (cs << 6) + (w << 4) + n16;
        dst[(size_t)(row - radj) * C_DIM + col] = o[cs][rt][r];
      }
  if (w == 0 && n16 == 0) {
#pragma unroll
    for (int rt = 0; rt < 2; ++rt)
#pragma unroll
      for (int r = 0; r < 4; ++r) {
        const int row = row0 + (rt << 4) + (qd << 2) + r;
        ml[(size_t)seg * T + row] = make_float2(m_i[rt][r], l_i[rt][r]);
      }
  }

  // ---- padded rows (< n_padd): uniform over ALL T keys
  if (seg == 0 && np > row0) {
    const int pc = min(np - row0, 32);
    const int c4 = tid << 2;
    float a[4] = {0.f, 0.f, 0.f, 0.f};
#pragma unroll
    for (int c = 0; c < 4; ++c) {
      const unsigned short* vr = vtb + (size_t)(c4 + c) * T;
      for (int j = 0; j < T; j += 8) {
        uint4 v = *(const uint4*)(vr + j);
        a[c] += bf2f(v.x & 0xffff) + bf2f(v.x >> 16) + bf2f(v.y & 0xffff) + bf2f(v.y >> 16)
              + bf2f(v.z & 0xffff) + bf2f(v.z >> 16) + bf2f(v.w & 0xffff) + bf2f(v.w >> 16);
      }
    }
    const float inv = 1.0f / (float)T;
    float4 rv = {a[0] * inv, a[1] * inv, a[2] * inv, a[3] * inv};
    for (int r = 0; r < pc; ++r)
      *(float4*)(out + (size_t)(row0 + r) * C_DIM + c4) = rv;
  }
}

// ---------------------------------------------------------------------------
// Kernel 3: merge up to 4 segments per row
// ---------------------------------------------------------------------------
__global__ __launch_bounds__(256) void attn_merge4(
    float* __restrict__ out, const float* __restrict__ part,
    const float2* __restrict__ ml, const int* __restrict__ np_p, int T) {
  const int row = blockIdx.x;
  if (row < *np_p) return;
  const int ns = (row >> 10) + 1;
  const int c = threadIdx.x << 2;
  float2 m0 = ml[row];
  if (ns == 1) {
    const float inv = 1.0f / m0.y;
    float4 o0 = *(const float4*)(out + (size_t)row * C_DIM + c);
    o0.x *= inv; o0.y *= inv; o0.z *= inv; o0.w *= inv;
    *(float4*)(out + (size_t)row * C_DIM + c) = o0;
    return;
  }
  float2 ms[3];
  float M = m0.x;
  for (int s = 1; s < ns; ++s) { ms[s-1] = ml[(size_t)s * T + row]; M = fmaxf(M, ms[s-1].x); }
  const float w0 = __expf(m0.x - M);
  float L = w0 * m0.y;
  float ws[3];
  for (int s = 1; s < ns; ++s) { ws[s-1] = __expf(ms[s-1].x - M); L += ws[s-1] * ms[s-1].y; }
  const float inv = 1.0f / L;
  float4 acc = *(const float4*)(out + (size_t)row * C_DIM + c);
  acc.x *= w0; acc.y *= w0; acc.z *= w0; acc.w *= w0;
  for (int s = 1; s < ns; ++s) {
    const float* pp = part + ((size_t)(s - 1) * T - (size_t)(s * (s - 1) / 2) * 1024) * C_DIM
                    + (size_t)(row - (s << 10)) * C_DIM + c;
    float4 p = *(const float4*)pp;
    acc.x += ws[s-1] * p.x; acc.y += ws[s-1] * p.y;
    acc.z += ws[s-1] * p.z; acc.w += ws[s-1] * p.w;
  }
  acc.x *= inv; acc.y *= inv; acc.z *= inv; acc.w *= inv;
  *(float4*)(out + (size_t)row * C_DIM + c) = acc;
}

// ---------------------------------------------------------------------------
extern "C" void kernel_launch(void* const* d_in, const int* in_sizes, int n_in,
                              void* d_out, int out_size, void* d_ws, size_t ws_size,
                              hipStream_t stream) {
  const float* x    = (const float*)d_in[0];
  const float* W    = (const float*)d_in[1];
  const float* b    = (const float*)d_in[2];
  const int* n_padd = (const int*)d_in[3];
  float* out = (float*)d_out;

  const int T = in_sizes[0] / C_DIM;
  unsigned short* qkb = (unsigned short*)d_ws;                    // [T][2048]   16 MB
  unsigned short* vtb = qkb + (size_t)T * QKS;                    // [1024][T]    8 MB
  unsigned short* xb  = vtb + (size_t)C_DIM * T;                  // [T][1024]    8 MB
  unsigned short* WT  = xb  + (size_t)T * C_DIM;                  // [3072][1024] 6 MB
  float* part = (float*)(WT + (size_t)3072 * C_DIM);              // 6144*1024   24 MB
  float2* ml  = (float2*)(part + (size_t)(3 * T - 6144) * C_DIM); // 4T float2

  cast_x<<<(T * C_DIM) / 1024, 256, 0, stream>>>(x, xb);
  transpose_w<<<dim3(48, 16), 256, 0, stream>>>(W, WT);

  // Q|K: [T][2048] = xb @ WT[0:2048]^T, bias per col
  gemm_bt<<<dim3(QKS / 128, T / 128), 256, 0, stream>>>(
      xb, WT, qkb, b, QKS, 0);
  // V^T: [1024][T] = WvT @ xb^T, bias per row (b offset by 2048)
  gemm_bt<<<dim3(T / 128, C_DIM / 128), 256, 0, stream>>>(
      WT + (size_t)QKS * C_DIM, xb, vtb, b + QKS, T, 1);

  const int ntiles = T / 32;
  int nblk = 0;
  for (int t = 0; t < ntiles; ++t) nblk += t / 32 + 1;
  attn_mfma<<<nblk, 256, 0, stream>>>(qkb, vtb, n_padd, out, part, ml, T, nblk);

  attn_merge4<<<T, 256, 0, stream>>>(out, part, ml, n_padd, T);
}

// Round 8
// 627.968 us; speedup vs baseline: 1.5176x; 1.1492x over previous
//
#include <hip/hip_runtime.h>
#include <hip/hip_bf16.h>
#include <math.h>

#define C_DIM 1024
#define QKS  2048    // Q|K row stride in bf16 workspace

typedef __attribute__((ext_vector_type(8))) short bf16x8;   // 8 bf16 = 4 VGPRs
typedef __attribute__((ext_vector_type(4))) float f32x4;    // MFMA C/D

__device__ __forceinline__ unsigned short f2bf(float f) {
  __hip_bfloat16 h = __float2bfloat16(f);
  return *(reinterpret_cast<unsigned short*>(&h));
}
__device__ __forceinline__ float bf2f(unsigned short u) {
  return __uint_as_float(((unsigned int)u) << 16);
}
__device__ __forceinline__ f32x4 mfma16(bf16x8 a, bf16x8 b, f32x4 c) {
  return __builtin_amdgcn_mfma_f32_16x16x32_bf16(a, b, c, 0, 0, 0);
}

// ---------------------------------------------------------------------------
// Kernel 0a: cast x (fp32) -> xb (bf16)
// ---------------------------------------------------------------------------
__global__ __launch_bounds__(256) void cast_x(
    const float* __restrict__ x, unsigned short* __restrict__ xb) {
  const int i = (blockIdx.x * 256 + threadIdx.x) << 2;
  float4 v = *(const float4*)(x + i);
  ushort4 u;
  u.x = f2bf(v.x); u.y = f2bf(v.y); u.z = f2bf(v.z); u.w = f2bf(v.w);
  *(ushort4*)(xb + i) = u;
}

// ---------------------------------------------------------------------------
// Kernel 0b: W [1024][3072] fp32 -> WT [3072][1024] bf16
// ---------------------------------------------------------------------------
__global__ __launch_bounds__(256) void transpose_w(
    const float* __restrict__ W, unsigned short* __restrict__ WT) {
  __shared__ float Ls[64][65];
  const int n0 = blockIdx.x * 64;
  const int k0 = blockIdx.y * 64;
  const int c = (threadIdx.x & 15) << 2;
  const int r = threadIdx.x >> 4;
#pragma unroll
  for (int rr = 0; rr < 64; rr += 16) {
    float4 v = *(const float4*)(W + (size_t)(k0 + r + rr) * 3072 + n0 + c);
    Ls[r + rr][c + 0] = v.x; Ls[r + rr][c + 1] = v.y;
    Ls[r + rr][c + 2] = v.z; Ls[r + rr][c + 3] = v.w;
  }
  __syncthreads();
#pragma unroll
  for (int rr = 0; rr < 64; rr += 16) {
    const int X = r + rr;
    ushort4 u;
    u.x = f2bf(Ls[c + 0][X]); u.y = f2bf(Ls[c + 1][X]);
    u.z = f2bf(Ls[c + 2][X]); u.w = f2bf(Ls[c + 3][X]);
    *(ushort4*)(WT + (size_t)(n0 + X) * C_DIM + k0 + c) = u;
  }
}

// ---------------------------------------------------------------------------
// Kernel 1: C = A @ BT^T + bias, bf16 MFMA, direct fragment loads.
// ---------------------------------------------------------------------------
__global__ __launch_bounds__(256) void gemm_bt(
    const unsigned short* __restrict__ A, const unsigned short* __restrict__ BT,
    unsigned short* __restrict__ C, const float* __restrict__ bias,
    int ldc, int bias_row) {
  const int tid = threadIdx.x, lane = tid & 63, w = tid >> 6;
  const int qd = lane >> 4, n16 = lane & 15;
  const int m0 = blockIdx.y * 128;
  const int n0 = blockIdx.x * 128 + (w << 5);

  f32x4 s[8][2];
#pragma unroll
  for (int mt = 0; mt < 8; ++mt)
#pragma unroll
    for (int j = 0; j < 2; ++j) s[mt][j] = (f32x4){0.f, 0.f, 0.f, 0.f};

  const unsigned short* ap = A + (size_t)(m0 + n16) * C_DIM + (qd << 3);
  const unsigned short* bp = BT + (size_t)(n0 + n16) * C_DIM + (qd << 3);

#pragma unroll 2
  for (int ks = 0; ks < C_DIM; ks += 32) {
    bf16x8 b0 = *(const bf16x8*)(bp + ks);
    bf16x8 b1 = *(const bf16x8*)(bp + (size_t)16 * C_DIM + ks);
#pragma unroll
    for (int mt = 0; mt < 8; ++mt) {
      bf16x8 a = *(const bf16x8*)(ap + (size_t)(mt << 4) * C_DIM + ks);
      s[mt][0] = mfma16(a, b0, s[mt][0]);
      s[mt][1] = mfma16(a, b1, s[mt][1]);
    }
  }

#pragma unroll
  for (int mt = 0; mt < 8; ++mt)
#pragma unroll
    for (int j = 0; j < 2; ++j) {
      const int col = n0 + (j << 4) + n16;
      const float bc = bias_row ? 0.f : bias[col];
#pragma unroll
      for (int r = 0; r < 4; ++r) {
        const int row = m0 + (mt << 4) + (qd << 2) + r;
        const float bv = bias_row ? bias[row] : bc;
        C[(size_t)row * ldc + col] = f2bf(s[mt][j][r] + bv);
      }
    }
}

// ---------------------------------------------------------------------------
// Kernel 2: flash attention, bf16 MFMA, BQ=32, 512-key segments -> 576 blocks
// (uniform 3-4 chunks of 128 keys each). seg0 writes fp32 to out; seg>=1
// writes bf16 partials. All o[][] indices static (no spill).
// ---------------------------------------------------------------------------
__global__ __launch_bounds__(256) void attn_mfma(
    const unsigned short* __restrict__ qkb, const unsigned short* __restrict__ vtb,
    const int* __restrict__ np_p, float* __restrict__ out,
    unsigned short* __restrict__ part, float2* __restrict__ ml, int T) {
  __shared__ __align__(16) unsigned short Ps[32][136];
  __shared__ float mw[4][32];
  __shared__ float lw[4][32];

  const int tid  = threadIdx.x;
  const int lane = tid & 63;
  const int w    = tid >> 6;
  const int qd   = lane >> 4;
  const int n16  = lane & 15;

  // block -> (tile, seg): group g has 16 tiles x (g+1) segs
  int rb = (int)blockIdx.x;
  int g = 0;
  while (rb >= 16 * (g + 1)) { rb -= 16 * (g + 1); ++g; }
  const int tile = g * 16 + (rb & 15);
  const int seg  = rb >> 4;
  const int nseg = g + 1;
  const int row0 = tile * 32;
  const int kmax = row0 + 32;
  const int nch  = (kmax + 127) >> 7;
  const int cbase = nch / nseg, cext = nch % nseg;
  const int ch0 = seg * cbase + (seg < cext ? seg : cext);
  const int ch1 = ch0 + cbase + (seg < cext ? 1 : 0);
  const int np = *np_p;

  f32x4 o[16][2];
#pragma unroll
  for (int cs = 0; cs < 16; ++cs)
#pragma unroll
    for (int rt = 0; rt < 2; ++rt) o[cs][rt] = (f32x4){0.f, 0.f, 0.f, 0.f};
  float m_i[2][4], l_i[2][4];
#pragma unroll
  for (int rt = 0; rt < 2; ++rt)
#pragma unroll
    for (int r = 0; r < 4; ++r) { m_i[rt][r] = -3.0e38f; l_i[rt][r] = 0.f; }

  const unsigned short* qrow0 = qkb + (size_t)(row0 + n16) * QKS + (qd << 3);
  const unsigned short* qrow1 = qkb + (size_t)(row0 + 16 + n16) * QKS + (qd << 3);

  for (int ch = ch0; ch < ch1; ++ch) {
    const int kc0 = ch << 7;
    f32x4 s[2][2];
#pragma unroll
    for (int rt = 0; rt < 2; ++rt)
#pragma unroll
      for (int kt = 0; kt < 2; ++kt) s[rt][kt] = (f32x4){0.f, 0.f, 0.f, 0.f};

    // ---- S = Q K^T : direct global fragment loads
    const unsigned short* krow0 =
        qkb + (size_t)(kc0 + (w << 5) + n16) * QKS + C_DIM + (qd << 3);
    const unsigned short* krow1 = krow0 + (size_t)16 * QKS;
#pragma unroll 4
    for (int ks = 0; ks < C_DIM; ks += 32) {
      bf16x8 a0 = *(const bf16x8*)(qrow0 + ks);
      bf16x8 a1 = *(const bf16x8*)(qrow1 + ks);
      bf16x8 b0 = *(const bf16x8*)(krow0 + ks);
      bf16x8 b1 = *(const bf16x8*)(krow1 + ks);
      s[0][0] = mfma16(a0, b0, s[0][0]);
      s[0][1] = mfma16(a0, b1, s[0][1]);
      s[1][0] = mfma16(a1, b0, s[1][0]);
      s[1][1] = mfma16(a1, b1, s[1][1]);
    }

    // ---- online softmax
    float al[2][4];
#pragma unroll
    for (int rt = 0; rt < 2; ++rt) {
#pragma unroll
      for (int r = 0; r < 4; ++r) {
        const int rowg = row0 + (rt << 4) + (qd << 2) + r;
        const int j0 = kc0 + (w << 5) + n16;
        const int j1 = j0 + 16;
        float sv0 = ((j0 <= rowg) && (j0 >= np)) ? s[rt][0][r] * 0.03125f : -3.0e38f;
        float sv1 = ((j1 <= rowg) && (j1 >= np)) ? s[rt][1][r] * 0.03125f : -3.0e38f;
        s[rt][0][r] = sv0; s[rt][1][r] = sv1;
        float m2 = fmaxf(sv0, sv1);
        m2 = fmaxf(m2, __shfl_xor(m2, 1));
        m2 = fmaxf(m2, __shfl_xor(m2, 2));
        m2 = fmaxf(m2, __shfl_xor(m2, 4));
        m2 = fmaxf(m2, __shfl_xor(m2, 8));
        if (n16 == r) mw[w][(rt << 4) + (qd << 2) + r] = m2;
      }
    }
    __syncthreads();
#pragma unroll
    for (int rt = 0; rt < 2; ++rt) {
#pragma unroll
      for (int r = 0; r < 4; ++r) {
        const int row = (rt << 4) + (qd << 2) + r;
        float mn = fmaxf(fmaxf(mw[0][row], mw[1][row]), fmaxf(mw[2][row], mw[3][row]));
        mn = fmaxf(mn, m_i[rt][r]);
        al[rt][r] = __expf(m_i[rt][r] - mn);
        m_i[rt][r] = mn;
        float p0 = (s[rt][0][r] > -1.0e30f) ? __expf(s[rt][0][r] - mn) : 0.f;
        float p1 = (s[rt][1][r] > -1.0e30f) ? __expf(s[rt][1][r] - mn) : 0.f;
        Ps[row][(w << 5) + n16]      = f2bf(p0);
        Ps[row][(w << 5) + 16 + n16] = f2bf(p1);
        float ls = p0 + p1;
        ls += __shfl_xor(ls, 1);
        ls += __shfl_xor(ls, 2);
        ls += __shfl_xor(ls, 4);
        ls += __shfl_xor(ls, 8);
        if (n16 == r) lw[w][row] = ls;
      }
    }
    __syncthreads();
#pragma unroll
    for (int rt = 0; rt < 2; ++rt)
#pragma unroll
      for (int r = 0; r < 4; ++r) {
        const int row = (rt << 4) + (qd << 2) + r;
        l_i[rt][r] = l_i[rt][r] * al[rt][r] +
                     (lw[0][row] + lw[1][row] + lw[2][row] + lw[3][row]);
      }
#pragma unroll
    for (int cs = 0; cs < 16; ++cs)
#pragma unroll
      for (int rt = 0; rt < 2; ++rt) {
        o[cs][rt][0] *= al[rt][0];
        o[cs][rt][1] *= al[rt][1];
        o[cs][rt][2] *= al[rt][2];
        o[cs][rt][3] *= al[rt][3];
      }

    // ---- O += P V : kb-outer / cs-inner, fully unrolled
#pragma unroll
    for (int kb = 0; kb < 4; ++kb) {
      const int kk = (kb << 5) + (qd << 3);
      bf16x8 pa0 = *(const bf16x8*)&Ps[n16][kk];
      bf16x8 pa1 = *(const bf16x8*)&Ps[16 + n16][kk];
      const unsigned short* vtp =
          vtb + (size_t)((w << 4) + n16) * T + kc0 + (qd << 3) + (kb << 5);
#pragma unroll
      for (int cs = 0; cs < 16; ++cs) {
        bf16x8 vb = *(const bf16x8*)(vtp + (size_t)(cs << 6) * T);
        o[cs][0] = mfma16(pa0, vb, o[cs][0]);
        o[cs][1] = mfma16(pa1, vb, o[cs][1]);
      }
    }
  }

  // ---- epilogue
  if (seg == 0) {
#pragma unroll
    for (int cs = 0; cs < 16; ++cs)
#pragma unroll
      for (int rt = 0; rt < 2; ++rt)
#pragma unroll
        for (int r = 0; r < 4; ++r) {
          const int row = row0 + (rt << 4) + (qd << 2) + r;
          const int col = (cs << 6) + (w << 4) + n16;
          out[(size_t)row * C_DIM + col] = o[cs][rt][r];
        }
  } else {
    const int slot = 8 * g * (g - 1) + (tile - 16 * g) * g + seg - 1;
    unsigned short* pd = part + (size_t)slot * 32 * C_DIM;
#pragma unroll
    for (int cs = 0; cs < 16; ++cs)
#pragma unroll
      for (int rt = 0; rt < 2; ++rt)
#pragma unroll
        for (int r = 0; r < 4; ++r) {
          const int rl = (rt << 4) + (qd << 2) + r;
          const int col = (cs << 6) + (w << 4) + n16;
          pd[(size_t)rl * C_DIM + col] = f2bf(o[cs][rt][r]);
        }
  }
  if (w == 0 && n16 == 0) {
#pragma unroll
    for (int rt = 0; rt < 2; ++rt)
#pragma unroll
      for (int r = 0; r < 4; ++r) {
        const int row = row0 + (rt << 4) + (qd << 2) + r;
        ml[(size_t)seg * T + row] = make_float2(m_i[rt][r], l_i[rt][r]);
      }
  }

  // ---- padded rows (< n_padd): uniform over ALL T keys
  if (seg == 0 && np > row0) {
    const int pc = min(np - row0, 32);
    const int c4 = tid << 2;
    float a[4] = {0.f, 0.f, 0.f, 0.f};
#pragma unroll
    for (int c = 0; c < 4; ++c) {
      const unsigned short* vr = vtb + (size_t)(c4 + c) * T;
      for (int j = 0; j < T; j += 8) {
        uint4 v = *(const uint4*)(vr + j);
        a[c] += bf2f(v.x & 0xffff) + bf2f(v.x >> 16) + bf2f(v.y & 0xffff) + bf2f(v.y >> 16)
              + bf2f(v.z & 0xffff) + bf2f(v.z >> 16) + bf2f(v.w & 0xffff) + bf2f(v.w >> 16);
      }
    }
    const float inv = 1.0f / (float)T;
    float4 rv = {a[0] * inv, a[1] * inv, a[2] * inv, a[3] * inv};
    for (int r = 0; r < pc; ++r)
      *(float4*)(out + (size_t)(row0 + r) * C_DIM + c4) = rv;
  }
}

// ---------------------------------------------------------------------------
// Kernel 3: merge up to 8 segments per row (bf16 partials)
// ---------------------------------------------------------------------------
__global__ __launch_bounds__(256) void attn_mergeN(
    float* __restrict__ out, const unsigned short* __restrict__ part,
    const float2* __restrict__ ml, const int* __restrict__ np_p, int T) {
  const int row = blockIdx.x;
  if (row < *np_p) return;
  const int tile = row >> 5;
  const int G = tile >> 4;
  const int ns = G + 1;
  const int c = threadIdx.x << 2;
  float2 m0 = ml[row];
  if (ns == 1) {
    const float inv = 1.0f / m0.y;
    float4 o0 = *(const float4*)(out + (size_t)row * C_DIM + c);
    o0.x *= inv; o0.y *= inv; o0.z *= inv; o0.w *= inv;
    *(float4*)(out + (size_t)row * C_DIM + c) = o0;
    return;
  }
  float2 ms[8];
  float M = m0.x;
  for (int s = 1; s < ns; ++s) { ms[s] = ml[(size_t)s * T + row]; M = fmaxf(M, ms[s].x); }
  const float w0 = __expf(m0.x - M);
  float L = w0 * m0.y;
  float ws[8];
  for (int s = 1; s < ns; ++s) { ws[s] = __expf(ms[s].x - M); L += ws[s] * ms[s].y; }
  const float inv = 1.0f / L;
  float4 acc = *(const float4*)(out + (size_t)row * C_DIM + c);
  acc.x *= w0; acc.y *= w0; acc.z *= w0; acc.w *= w0;
  const int base_slot = 8 * G * (G - 1) + (tile - 16 * G) * G;
  for (int s = 1; s < ns; ++s) {
    const unsigned short* pr =
        part + ((size_t)(base_slot + s - 1) * 32 + (row & 31)) * C_DIM + c;
    ushort4 u = *(const ushort4*)pr;
    acc.x += ws[s] * bf2f(u.x); acc.y += ws[s] * bf2f(u.y);
    acc.z += ws[s] * bf2f(u.z); acc.w += ws[s] * bf2f(u.w);
  }
  acc.x *= inv; acc.y *= inv; acc.z *= inv; acc.w *= inv;
  *(float4*)(out + (size_t)row * C_DIM + c) = acc;
}

// ---------------------------------------------------------------------------
extern "C" void kernel_launch(void* const* d_in, const int* in_sizes, int n_in,
                              void* d_out, int out_size, void* d_ws, size_t ws_size,
                              hipStream_t stream) {
  const float* x    = (const float*)d_in[0];
  const float* W    = (const float*)d_in[1];
  const float* b    = (const float*)d_in[2];
  const int* n_padd = (const int*)d_in[3];
  float* out = (float*)d_out;

  const int T = in_sizes[0] / C_DIM;
  // ws layout (overlapping lifetimes):
  //   [0,16M)   qkb [T][2048] bf16          (persistent)
  //   [16,24M)  vtb [1024][T] bf16          (persistent)
  //   [24M...)  PHASE 1: xb [T][1024] bf16 (8M) + WT [3072][1024] bf16 (6M)
  //             PHASE 2 (after gemms): part bf16, 448 slots x 32 x 1024 (28.7M)
  //   tail: ml 8*T float2
  unsigned short* qkb = (unsigned short*)d_ws;
  unsigned short* vtb = qkb + (size_t)T * QKS;
  unsigned short* xb  = vtb + (size_t)C_DIM * T;
  unsigned short* WT  = xb  + (size_t)T * C_DIM;
  unsigned short* part = xb;                                   // overlays xb+WT
  float2* ml = (float2*)(part + (size_t)448 * 32 * C_DIM);
  // total: 24M + 28.7M + 64K  (< R7's 63M footprint)

  cast_x<<<(T * C_DIM) / 1024, 256, 0, stream>>>(x, xb);
  transpose_w<<<dim3(48, 16), 256, 0, stream>>>(W, WT);

  gemm_bt<<<dim3(QKS / 128, T / 128), 256, 0, stream>>>(
      xb, WT, qkb, b, QKS, 0);
  gemm_bt<<<dim3(T / 128, C_DIM / 128), 256, 0, stream>>>(
      WT + (size_t)QKS * C_DIM, xb, vtb, b + QKS, T, 1);

  const int ntiles = T / 32;
  int nblk = 0;
  for (int t = 0; t < ntiles; ++t) nblk += (t >> 4) + 1;   // 576 @ T=4096
  attn_mfma<<<nblk, 256, 0, stream>>>(qkb, vtb, n_padd, out, part, ml, T);

  attn_mergeN<<<T, 256, 0, stream>>>(out, part, ml, n_padd, T);
}

// Round 9
// 617.112 us; speedup vs baseline: 1.5443x; 1.0176x over previous
//
#include <hip/hip_runtime.h>
#include <hip/hip_bf16.h>
#include <math.h>

#define C_DIM 1024
#define QKS  2048    // Q|K row stride in bf16 workspace

typedef __attribute__((ext_vector_type(8))) short bf16x8;   // 8 bf16 = 4 VGPRs
typedef __attribute__((ext_vector_type(4))) float f32x4;    // MFMA C/D

__device__ __forceinline__ unsigned short f2bf(float f) {
  __hip_bfloat16 h = __float2bfloat16(f);
  return *(reinterpret_cast<unsigned short*>(&h));
}
__device__ __forceinline__ float bf2f(unsigned short u) {
  return __uint_as_float(((unsigned int)u) << 16);
}
__device__ __forceinline__ f32x4 mfma16(bf16x8 a, bf16x8 b, f32x4 c) {
  return __builtin_amdgcn_mfma_f32_16x16x32_bf16(a, b, c, 0, 0, 0);
}

// ---------------------------------------------------------------------------
// Kernel 0a: cast x (fp32) -> xb (bf16)
// ---------------------------------------------------------------------------
__global__ __launch_bounds__(256) void cast_x(
    const float* __restrict__ x, unsigned short* __restrict__ xb) {
  const int i = (blockIdx.x * 256 + threadIdx.x) << 2;
  float4 v = *(const float4*)(x + i);
  ushort4 u;
  u.x = f2bf(v.x); u.y = f2bf(v.y); u.z = f2bf(v.z); u.w = f2bf(v.w);
  *(ushort4*)(xb + i) = u;
}

// ---------------------------------------------------------------------------
// Kernel 0b: W [1024][3072] fp32 -> WT [3072][1024] bf16
// ---------------------------------------------------------------------------
__global__ __launch_bounds__(256) void transpose_w(
    const float* __restrict__ W, unsigned short* __restrict__ WT) {
  __shared__ float Ls[64][65];
  const int n0 = blockIdx.x * 64;
  const int k0 = blockIdx.y * 64;
  const int c = (threadIdx.x & 15) << 2;
  const int r = threadIdx.x >> 4;
#pragma unroll
  for (int rr = 0; rr < 64; rr += 16) {
    float4 v = *(const float4*)(W + (size_t)(k0 + r + rr) * 3072 + n0 + c);
    Ls[r + rr][c + 0] = v.x; Ls[r + rr][c + 1] = v.y;
    Ls[r + rr][c + 2] = v.z; Ls[r + rr][c + 3] = v.w;
  }
  __syncthreads();
#pragma unroll
  for (int rr = 0; rr < 64; rr += 16) {
    const int X = r + rr;
    ushort4 u;
    u.x = f2bf(Ls[c + 0][X]); u.y = f2bf(Ls[c + 1][X]);
    u.z = f2bf(Ls[c + 2][X]); u.w = f2bf(Ls[c + 3][X]);
    *(ushort4*)(WT + (size_t)(n0 + X) * C_DIM + k0 + c) = u;
  }
}

// ---------------------------------------------------------------------------
// Kernel 1: C = A @ BT^T + bias, bf16 MFMA, direct fragment loads.
// MLP: all 10 loads of a k-step issued before the 16 MFMAs consume them.
// ---------------------------------------------------------------------------
__global__ __launch_bounds__(256) void gemm_bt(
    const unsigned short* __restrict__ A, const unsigned short* __restrict__ BT,
    unsigned short* __restrict__ C, const float* __restrict__ bias,
    int ldc, int bias_row) {
  const int tid = threadIdx.x, lane = tid & 63, w = tid >> 6;
  const int qd = lane >> 4, n16 = lane & 15;
  const int m0 = blockIdx.y * 128;
  const int n0 = blockIdx.x * 128 + (w << 5);

  f32x4 s[8][2];
#pragma unroll
  for (int mt = 0; mt < 8; ++mt)
#pragma unroll
    for (int j = 0; j < 2; ++j) s[mt][j] = (f32x4){0.f, 0.f, 0.f, 0.f};

  const unsigned short* ap = A + (size_t)(m0 + n16) * C_DIM + (qd << 3);
  const unsigned short* bp = BT + (size_t)(n0 + n16) * C_DIM + (qd << 3);

#pragma unroll 2
  for (int ks = 0; ks < C_DIM; ks += 32) {
    bf16x8 b0 = *(const bf16x8*)(bp + ks);
    bf16x8 b1 = *(const bf16x8*)(bp + (size_t)16 * C_DIM + ks);
    bf16x8 a[8];
#pragma unroll
    for (int mt = 0; mt < 8; ++mt)
      a[mt] = *(const bf16x8*)(ap + (size_t)(mt << 4) * C_DIM + ks);
#pragma unroll
    for (int mt = 0; mt < 8; ++mt) {
      s[mt][0] = mfma16(a[mt], b0, s[mt][0]);
      s[mt][1] = mfma16(a[mt], b1, s[mt][1]);
    }
  }

#pragma unroll
  for (int mt = 0; mt < 8; ++mt)
#pragma unroll
    for (int j = 0; j < 2; ++j) {
      const int col = n0 + (j << 4) + n16;
      const float bc = bias_row ? 0.f : bias[col];
#pragma unroll
      for (int r = 0; r < 4; ++r) {
        const int row = m0 + (mt << 4) + (qd << 2) + r;
        const float bv = bias_row ? bias[row] : bc;
        C[(size_t)row * ldc + col] = f2bf(s[mt][j][r] + bv);
      }
    }
}

// ---------------------------------------------------------------------------
// Kernel 2: flash attention, bf16 MFMA, BQ=32, 512-key segments.
// MLP-batched: S-phase issues 16 frag loads per batch before 16 MFMAs
// (8 batches/chunk); PV issues 4 V loads per batch before 8 MFMAs.
// ---------------------------------------------------------------------------
__global__ __launch_bounds__(256) void attn_mfma(
    const unsigned short* __restrict__ qkb, const unsigned short* __restrict__ vtb,
    const int* __restrict__ np_p, float* __restrict__ out,
    unsigned short* __restrict__ part, float2* __restrict__ ml, int T) {
  __shared__ __align__(16) unsigned short Ps[32][136];
  __shared__ float mw[4][32];
  __shared__ float lw[4][32];

  const int tid  = threadIdx.x;
  const int lane = tid & 63;
  const int w    = tid >> 6;
  const int qd   = lane >> 4;
  const int n16  = lane & 15;

  // block -> (tile, seg): group g has 16 tiles x (g+1) segs
  int rb = (int)blockIdx.x;
  int g = 0;
  while (rb >= 16 * (g + 1)) { rb -= 16 * (g + 1); ++g; }
  const int tile = g * 16 + (rb & 15);
  const int seg  = rb >> 4;
  const int nseg = g + 1;
  const int row0 = tile * 32;
  const int kmax = row0 + 32;
  const int nch  = (kmax + 127) >> 7;
  const int cbase = nch / nseg, cext = nch % nseg;
  const int ch0 = seg * cbase + (seg < cext ? seg : cext);
  const int ch1 = ch0 + cbase + (seg < cext ? 1 : 0);
  const int np = *np_p;

  f32x4 o[16][2];
#pragma unroll
  for (int cs = 0; cs < 16; ++cs)
#pragma unroll
    for (int rt = 0; rt < 2; ++rt) o[cs][rt] = (f32x4){0.f, 0.f, 0.f, 0.f};
  float m_i[2][4], l_i[2][4];
#pragma unroll
  for (int rt = 0; rt < 2; ++rt)
#pragma unroll
    for (int r = 0; r < 4; ++r) { m_i[rt][r] = -3.0e38f; l_i[rt][r] = 0.f; }

  const unsigned short* qrow0 = qkb + (size_t)(row0 + n16) * QKS + (qd << 3);
  const unsigned short* qrow1 = qkb + (size_t)(row0 + 16 + n16) * QKS + (qd << 3);

  for (int ch = ch0; ch < ch1; ++ch) {
    const int kc0 = ch << 7;
    f32x4 s[2][2];
#pragma unroll
    for (int rt = 0; rt < 2; ++rt)
#pragma unroll
      for (int kt = 0; kt < 2; ++kt) s[rt][kt] = (f32x4){0.f, 0.f, 0.f, 0.f};

    // ---- S = Q K^T : batched direct global fragment loads (16 in flight)
    const unsigned short* krow0 =
        qkb + (size_t)(kc0 + (w << 5) + n16) * QKS + C_DIM + (qd << 3);
    const unsigned short* krow1 = krow0 + (size_t)16 * QKS;
#pragma unroll
    for (int bt = 0; bt < 8; ++bt) {
      bf16x8 fa0[4], fa1[4], fb0[4], fb1[4];
#pragma unroll
      for (int u = 0; u < 4; ++u) {
        const int ks = (bt << 7) + (u << 5);
        fa0[u] = *(const bf16x8*)(qrow0 + ks);
        fa1[u] = *(const bf16x8*)(qrow1 + ks);
        fb0[u] = *(const bf16x8*)(krow0 + ks);
        fb1[u] = *(const bf16x8*)(krow1 + ks);
      }
#pragma unroll
      for (int u = 0; u < 4; ++u) {
        s[0][0] = mfma16(fa0[u], fb0[u], s[0][0]);
        s[0][1] = mfma16(fa0[u], fb1[u], s[0][1]);
        s[1][0] = mfma16(fa1[u], fb0[u], s[1][0]);
        s[1][1] = mfma16(fa1[u], fb1[u], s[1][1]);
      }
    }

    // ---- online softmax
    float al[2][4];
#pragma unroll
    for (int rt = 0; rt < 2; ++rt) {
#pragma unroll
      for (int r = 0; r < 4; ++r) {
        const int rowg = row0 + (rt << 4) + (qd << 2) + r;
        const int j0 = kc0 + (w << 5) + n16;
        const int j1 = j0 + 16;
        float sv0 = ((j0 <= rowg) && (j0 >= np)) ? s[rt][0][r] * 0.03125f : -3.0e38f;
        float sv1 = ((j1 <= rowg) && (j1 >= np)) ? s[rt][1][r] * 0.03125f : -3.0e38f;
        s[rt][0][r] = sv0; s[rt][1][r] = sv1;
        float m2 = fmaxf(sv0, sv1);
        m2 = fmaxf(m2, __shfl_xor(m2, 1));
        m2 = fmaxf(m2, __shfl_xor(m2, 2));
        m2 = fmaxf(m2, __shfl_xor(m2, 4));
        m2 = fmaxf(m2, __shfl_xor(m2, 8));
        if (n16 == r) mw[w][(rt << 4) + (qd << 2) + r] = m2;
      }
    }
    __syncthreads();
#pragma unroll
    for (int rt = 0; rt < 2; ++rt) {
#pragma unroll
      for (int r = 0; r < 4; ++r) {
        const int row = (rt << 4) + (qd << 2) + r;
        float mn = fmaxf(fmaxf(mw[0][row], mw[1][row]), fmaxf(mw[2][row], mw[3][row]));
        mn = fmaxf(mn, m_i[rt][r]);
        al[rt][r] = __expf(m_i[rt][r] - mn);
        m_i[rt][r] = mn;
        float p0 = (s[rt][0][r] > -1.0e30f) ? __expf(s[rt][0][r] - mn) : 0.f;
        float p1 = (s[rt][1][r] > -1.0e30f) ? __expf(s[rt][1][r] - mn) : 0.f;
        Ps[row][(w << 5) + n16]      = f2bf(p0);
        Ps[row][(w << 5) + 16 + n16] = f2bf(p1);
        float ls = p0 + p1;
        ls += __shfl_xor(ls, 1);
        ls += __shfl_xor(ls, 2);
        ls += __shfl_xor(ls, 4);
        ls += __shfl_xor(ls, 8);
        if (n16 == r) lw[w][row] = ls;
      }
    }
    __syncthreads();
#pragma unroll
    for (int rt = 0; rt < 2; ++rt)
#pragma unroll
      for (int r = 0; r < 4; ++r) {
        const int row = (rt << 4) + (qd << 2) + r;
        l_i[rt][r] = l_i[rt][r] * al[rt][r] +
                     (lw[0][row] + lw[1][row] + lw[2][row] + lw[3][row]);
      }
#pragma unroll
    for (int cs = 0; cs < 16; ++cs)
#pragma unroll
      for (int rt = 0; rt < 2; ++rt) {
        o[cs][rt][0] *= al[rt][0];
        o[cs][rt][1] *= al[rt][1];
        o[cs][rt][2] *= al[rt][2];
        o[cs][rt][3] *= al[rt][3];
      }

    // ---- O += P V : batched V loads (4 in flight per 8 MFMAs)
#pragma unroll
    for (int kb = 0; kb < 4; ++kb) {
      const int kk = (kb << 5) + (qd << 3);
      bf16x8 pa0 = *(const bf16x8*)&Ps[n16][kk];
      bf16x8 pa1 = *(const bf16x8*)&Ps[16 + n16][kk];
      const unsigned short* vtp =
          vtb + (size_t)((w << 4) + n16) * T + kc0 + (qd << 3) + (kb << 5);
#pragma unroll
      for (int cb = 0; cb < 4; ++cb) {
        bf16x8 vb[4];
#pragma unroll
        for (int u = 0; u < 4; ++u)
          vb[u] = *(const bf16x8*)(vtp + (size_t)(((cb << 2) + u) << 6) * T);
#pragma unroll
        for (int u = 0; u < 4; ++u) {
          const int cs = (cb << 2) + u;
          o[cs][0] = mfma16(pa0, vb[u], o[cs][0]);
          o[cs][1] = mfma16(pa1, vb[u], o[cs][1]);
        }
      }
    }
  }

  // ---- epilogue
  if (seg == 0) {
#pragma unroll
    for (int cs = 0; cs < 16; ++cs)
#pragma unroll
      for (int rt = 0; rt < 2; ++rt)
#pragma unroll
        for (int r = 0; r < 4; ++r) {
          const int row = row0 + (rt << 4) + (qd << 2) + r;
          const int col = (cs << 6) + (w << 4) + n16;
          out[(size_t)row * C_DIM + col] = o[cs][rt][r];
        }
  } else {
    const int slot = 8 * g * (g - 1) + (tile - 16 * g) * g + seg - 1;
    unsigned short* pd = part + (size_t)slot * 32 * C_DIM;
#pragma unroll
    for (int cs = 0; cs < 16; ++cs)
#pragma unroll
      for (int rt = 0; rt < 2; ++rt)
#pragma unroll
        for (int r = 0; r < 4; ++r) {
          const int rl = (rt << 4) + (qd << 2) + r;
          const int col = (cs << 6) + (w << 4) + n16;
          pd[(size_t)rl * C_DIM + col] = f2bf(o[cs][rt][r]);
        }
  }
  if (w == 0 && n16 == 0) {
#pragma unroll
    for (int rt = 0; rt < 2; ++rt)
#pragma unroll
      for (int r = 0; r < 4; ++r) {
        const int row = row0 + (rt << 4) + (qd << 2) + r;
        ml[(size_t)seg * T + row] = make_float2(m_i[rt][r], l_i[rt][r]);
      }
  }

  // ---- padded rows (< n_padd): uniform over ALL T keys
  if (seg == 0 && np > row0) {
    const int pc = min(np - row0, 32);
    const int c4 = tid << 2;
    float a[4] = {0.f, 0.f, 0.f, 0.f};
#pragma unroll
    for (int c = 0; c < 4; ++c) {
      const unsigned short* vr = vtb + (size_t)(c4 + c) * T;
      for (int j = 0; j < T; j += 8) {
        uint4 v = *(const uint4*)(vr + j);
        a[c] += bf2f(v.x & 0xffff) + bf2f(v.x >> 16) + bf2f(v.y & 0xffff) + bf2f(v.y >> 16)
              + bf2f(v.z & 0xffff) + bf2f(v.z >> 16) + bf2f(v.w & 0xffff) + bf2f(v.w >> 16);
      }
    }
    const float inv = 1.0f / (float)T;
    float4 rv = {a[0] * inv, a[1] * inv, a[2] * inv, a[3] * inv};
    for (int r = 0; r < pc; ++r)
      *(float4*)(out + (size_t)(row0 + r) * C_DIM + c4) = rv;
  }
}

// ---------------------------------------------------------------------------
// Kernel 3: merge up to 8 segments per row (bf16 partials)
// ---------------------------------------------------------------------------
__global__ __launch_bounds__(256) void attn_mergeN(
    float* __restrict__ out, const unsigned short* __restrict__ part,
    const float2* __restrict__ ml, const int* __restrict__ np_p, int T) {
  const int row = blockIdx.x;
  if (row < *np_p) return;
  const int tile = row >> 5;
  const int G = tile >> 4;
  const int ns = G + 1;
  const int c = threadIdx.x << 2;
  float2 m0 = ml[row];
  if (ns == 1) {
    const float inv = 1.0f / m0.y;
    float4 o0 = *(const float4*)(out + (size_t)row * C_DIM + c);
    o0.x *= inv; o0.y *= inv; o0.z *= inv; o0.w *= inv;
    *(float4*)(out + (size_t)row * C_DIM + c) = o0;
    return;
  }
  float2 ms[8];
  float M = m0.x;
  for (int s = 1; s < ns; ++s) { ms[s] = ml[(size_t)s * T + row]; M = fmaxf(M, ms[s].x); }
  const float w0 = __expf(m0.x - M);
  float L = w0 * m0.y;
  float ws[8];
  for (int s = 1; s < ns; ++s) { ws[s] = __expf(ms[s].x - M); L += ws[s] * ms[s].y; }
  const float inv = 1.0f / L;
  float4 acc = *(const float4*)(out + (size_t)row * C_DIM + c);
  acc.x *= w0; acc.y *= w0; acc.z *= w0; acc.w *= w0;
  const int base_slot = 8 * G * (G - 1) + (tile - 16 * G) * G;
  for (int s = 1; s < ns; ++s) {
    const unsigned short* pr =
        part + ((size_t)(base_slot + s - 1) * 32 + (row & 31)) * C_DIM + c;
    ushort4 u = *(const ushort4*)pr;
    acc.x += ws[s] * bf2f(u.x); acc.y += ws[s] * bf2f(u.y);
    acc.z += ws[s] * bf2f(u.z); acc.w += ws[s] * bf2f(u.w);
  }
  acc.x *= inv; acc.y *= inv; acc.z *= inv; acc.w *= inv;
  *(float4*)(out + (size_t)row * C_DIM + c) = acc;
}

// ---------------------------------------------------------------------------
extern "C" void kernel_launch(void* const* d_in, const int* in_sizes, int n_in,
                              void* d_out, int out_size, void* d_ws, size_t ws_size,
                              hipStream_t stream) {
  const float* x    = (const float*)d_in[0];
  const float* W    = (const float*)d_in[1];
  const float* b    = (const float*)d_in[2];
  const int* n_padd = (const int*)d_in[3];
  float* out = (float*)d_out;

  const int T = in_sizes[0] / C_DIM;
  // ws layout (overlapping lifetimes):
  //   [0,16M)   qkb [T][2048] bf16          (persistent)
  //   [16,24M)  vtb [1024][T] bf16          (persistent)
  //   [24M...)  PHASE 1: xb [T][1024] bf16 (8M) + WT [3072][1024] bf16 (6M)
  //             PHASE 2 (after gemms): part bf16, 448 slots x 32 x 1024 (28.7M)
  //   tail: ml 8*T float2
  unsigned short* qkb = (unsigned short*)d_ws;
  unsigned short* vtb = qkb + (size_t)T * QKS;
  unsigned short* xb  = vtb + (size_t)C_DIM * T;
  unsigned short* WT  = xb  + (size_t)T * C_DIM;
  unsigned short* part = xb;                                   // overlays xb+WT
  float2* ml = (float2*)(part + (size_t)448 * 32 * C_DIM);

  cast_x<<<(T * C_DIM) / 1024, 256, 0, stream>>>(x, xb);
  transpose_w<<<dim3(48, 16), 256, 0, stream>>>(W, WT);

  gemm_bt<<<dim3(QKS / 128, T / 128), 256, 0, stream>>>(
      xb, WT, qkb, b, QKS, 0);
  gemm_bt<<<dim3(T / 128, C_DIM / 128), 256, 0, stream>>>(
      WT + (size_t)QKS * C_DIM, xb, vtb, b + QKS, T, 1);

  const int ntiles = T / 32;
  int nblk = 0;
  for (int t = 0; t < ntiles; ++t) nblk += (t >> 4) + 1;   // 576 @ T=4096
  attn_mfma<<<nblk, 256, 0, stream>>>(qkb, vtb, n_padd, out, part, ml, T);

  attn_mergeN<<<T, 256, 0, stream>>>(out, part, ml, n_padd, T);
}

// Round 10
// 237.469 us; speedup vs baseline: 4.0132x; 2.5987x over previous
//
#include <hip/hip_runtime.h>
#include <hip/hip_bf16.h>
#include <math.h>

#define C_DIM 1024
#define QKS  2048    // Q|K row stride in bf16 workspace

typedef __attribute__((ext_vector_type(8))) short bf16x8;   // 8 bf16 = 4 VGPRs
typedef __attribute__((ext_vector_type(4))) float f32x4;    // MFMA C/D

__device__ __forceinline__ unsigned short f2bf(float f) {
  __hip_bfloat16 h = __float2bfloat16(f);
  return *(reinterpret_cast<unsigned short*>(&h));
}
__device__ __forceinline__ float bf2f(unsigned short u) {
  return __uint_as_float(((unsigned int)u) << 16);
}
__device__ __forceinline__ f32x4 mfma16(bf16x8 a, bf16x8 b, f32x4 c) {
  return __builtin_amdgcn_mfma_f32_16x16x32_bf16(a, b, c, 0, 0, 0);
}

// ---------------------------------------------------------------------------
// Kernel 0a: cast x (fp32) -> xb (bf16)
// ---------------------------------------------------------------------------
__global__ __launch_bounds__(256) void cast_x(
    const float* __restrict__ x, unsigned short* __restrict__ xb) {
  const int i = (blockIdx.x * 256 + threadIdx.x) << 2;
  float4 v = *(const float4*)(x + i);
  ushort4 u;
  u.x = f2bf(v.x); u.y = f2bf(v.y); u.z = f2bf(v.z); u.w = f2bf(v.w);
  *(ushort4*)(xb + i) = u;
}

// ---------------------------------------------------------------------------
// Kernel 0b: W [1024][3072] fp32 -> WT [3072][1024] bf16
// ---------------------------------------------------------------------------
__global__ __launch_bounds__(256) void transpose_w(
    const float* __restrict__ W, unsigned short* __restrict__ WT) {
  __shared__ float Ls[64][65];
  const int n0 = blockIdx.x * 64;
  const int k0 = blockIdx.y * 64;
  const int c = (threadIdx.x & 15) << 2;
  const int r = threadIdx.x >> 4;
#pragma unroll
  for (int rr = 0; rr < 64; rr += 16) {
    float4 v = *(const float4*)(W + (size_t)(k0 + r + rr) * 3072 + n0 + c);
    Ls[r + rr][c + 0] = v.x; Ls[r + rr][c + 1] = v.y;
    Ls[r + rr][c + 2] = v.z; Ls[r + rr][c + 3] = v.w;
  }
  __syncthreads();
#pragma unroll
  for (int rr = 0; rr < 64; rr += 16) {
    const int X = r + rr;
    ushort4 u;
    u.x = f2bf(Ls[c + 0][X]); u.y = f2bf(Ls[c + 1][X]);
    u.z = f2bf(Ls[c + 2][X]); u.w = f2bf(Ls[c + 3][X]);
    *(ushort4*)(WT + (size_t)(n0 + X) * C_DIM + k0 + c) = u;
  }
}

// ---------------------------------------------------------------------------
// gemm128<MODE>: C = A @ BT^T (+bias / *scale), m93-style LDS-staged GEMM.
// 128x128 tile, BK=32, 256 threads, 4 waves x (8 m-tiles x 2 n-tiles).
// A [M][lda] bf16 k-contiguous; BT [N][ldb] bf16 k-contiguous.
// MODE 0: bf16 out, + bias[col]          (x@W -> Q|K)
// MODE 1: bf16 out, + bias[row]          (Wv^T@x^T -> V^T)
// MODE 2: bf16 out, * 1/32, lower-triangle tiles only    (S = Q K^T)
// MODE 3: fp32 out, causal k-limit, split-K atomics      (O = P V)
// ---------------------------------------------------------------------------
#define LSTR 40   // LDS row stride (elems): 80 B, 16B-aligned, ~2-4-way banks

template <int MODE>
__global__ __launch_bounds__(256) void gemm128(
    const unsigned short* __restrict__ A, const unsigned short* __restrict__ BT,
    void* __restrict__ Cv, const float* __restrict__ bias,
    int lda, int ldb, int ldc, int T) {
  __shared__ __align__(16) unsigned short As[128][LSTR];  // 10 KB
  __shared__ __align__(16) unsigned short Bs[128][LSTR];  // 10 KB

  const int tid = threadIdx.x, lane = tid & 63, w = tid >> 6;
  const int qd = lane >> 4, n16 = lane & 15;

  int m0, n0, kbeg, kend;
  bool use_atomic = false;
  if (MODE == 2) {
    if ((int)blockIdx.x > (int)blockIdx.y) return;   // upper-triangle: skip
    m0 = blockIdx.y * 128; n0 = blockIdx.x * 128; kbeg = 0; kend = C_DIM;
  } else if (MODE == 3) {
    const int nyt = T >> 7;
    const int ex  = nyt > 16 ? nyt - 16 : 0;
    const int by  = (int)blockIdx.y;
    int bi, seg;
    if (by < nyt) { bi = by; seg = 0; } else { bi = by - ex; seg = 1; }
    const int kc = (bi + 1) << 7;                    // causal key limit
    kbeg = seg ? 2048 : 0;
    kend = seg ? kc : (kc < 2048 ? kc : 2048);
    m0 = bi << 7; n0 = blockIdx.x * 128;
    use_atomic = (kc > 2048);                        // rows pre-zeroed
  } else {
    m0 = blockIdx.y * 128; n0 = blockIdx.x * 128; kbeg = 0; kend = C_DIM;
  }

  f32x4 s[8][2];
#pragma unroll
  for (int mt = 0; mt < 8; ++mt)
#pragma unroll
    for (int j = 0; j < 2; ++j) s[mt][j] = (f32x4){0.f, 0.f, 0.f, 0.f};

  // staging map: thread -> (row 0..127, k-half 0/16)
  const int sr = tid >> 1;
  const int sk = (tid & 1) << 4;
  const unsigned short* ag = A  + (size_t)(m0 + sr) * lda + kbeg + sk;
  const unsigned short* bg = BT + (size_t)(n0 + sr) * ldb + kbeg + sk;

  uint4 ga0 = *(const uint4*)(ag);
  uint4 ga1 = *(const uint4*)(ag + 8);
  uint4 gb0 = *(const uint4*)(bg);
  uint4 gb1 = *(const uint4*)(bg + 8);

  for (int kk = kbeg; kk < kend; kk += 32) {
    __syncthreads();
    *(uint4*)&As[sr][sk]     = ga0;
    *(uint4*)&As[sr][sk + 8] = ga1;
    *(uint4*)&Bs[sr][sk]     = gb0;
    *(uint4*)&Bs[sr][sk + 8] = gb1;
    const int off = kk - kbeg + 32;
    if (kk + 32 < kend) {          // prefetch next tile while LDS settles
      ga0 = *(const uint4*)(ag + off);
      ga1 = *(const uint4*)(ag + off + 8);
      gb0 = *(const uint4*)(bg + off);
      gb1 = *(const uint4*)(bg + off + 8);
    }
    __syncthreads();

    bf16x8 bf0 = *(const bf16x8*)&Bs[(w << 5) + n16][qd << 3];
    bf16x8 bf1 = *(const bf16x8*)&Bs[(w << 5) + 16 + n16][qd << 3];
#pragma unroll
    for (int mt = 0; mt < 8; ++mt) {
      bf16x8 af = *(const bf16x8*)&As[(mt << 4) + n16][qd << 3];
      s[mt][0] = mfma16(af, bf0, s[mt][0]);
      s[mt][1] = mfma16(af, bf1, s[mt][1]);
    }
  }

  // ---- epilogue
  if (MODE == 3) {
    float* C = (float*)Cv;
#pragma unroll
    for (int mt = 0; mt < 8; ++mt)
#pragma unroll
      for (int j = 0; j < 2; ++j) {
        const int col = n0 + (w << 5) + (j << 4) + n16;
#pragma unroll
        for (int r = 0; r < 4; ++r) {
          const int row = m0 + (mt << 4) + (qd << 2) + r;
          if (use_atomic) atomicAdd(&C[(size_t)row * ldc + col], s[mt][j][r]);
          else            C[(size_t)row * ldc + col] = s[mt][j][r];
        }
      }
  } else {
    unsigned short* C = (unsigned short*)Cv;
#pragma unroll
    for (int mt = 0; mt < 8; ++mt)
#pragma unroll
      for (int j = 0; j < 2; ++j) {
        const int col = n0 + (w << 5) + (j << 4) + n16;
        const float bc = (MODE == 0) ? bias[col] : 0.f;
#pragma unroll
        for (int r = 0; r < 4; ++r) {
          const int row = m0 + (mt << 4) + (qd << 2) + r;
          float v = s[mt][j][r];
          if (MODE == 0) v += bc;
          if (MODE == 1) v += bias[row];
          if (MODE == 2) v *= 0.03125f;
          C[(size_t)row * ldc + col] = f2bf(v);
        }
      }
  }
}

// ---------------------------------------------------------------------------
// softmax_rows: in-place row softmax on S -> P (bf16), causal+padding masked,
// normalized (P rows sum to 1). Rows < n_padd -> zeros (fixed up later).
// Each row writes keys [0, ceil128(i+1)) so PV's tile-wide K-loop reads 0s.
// ---------------------------------------------------------------------------
__global__ __launch_bounds__(256) void softmax_rows(
    unsigned short* __restrict__ P, const int* __restrict__ np_p, int T) {
  __shared__ float red[8];
  const int i = blockIdx.x;
  const int np = *np_p;
  const int klen = ((i >> 7) + 1) << 7;
  const int tid = threadIdx.x, lane = tid & 63, w = tid >> 6;
  const int j0 = tid << 4;
  unsigned short* rowp = P + (size_t)i * T;
  const bool act = j0 < klen;

  if (i < np) {
    if (act) {
      uint4 z = {0, 0, 0, 0};
      *(uint4*)(rowp + j0) = z;
      *(uint4*)(rowp + j0 + 8) = z;
    }
    return;
  }

  float v[16];
  float mx = -3.0e38f;
  if (act) {
    uint4 u0 = *(const uint4*)(rowp + j0);
    uint4 u1 = *(const uint4*)(rowp + j0 + 8);
    const unsigned int uu[8] = {u0.x, u0.y, u0.z, u0.w, u1.x, u1.y, u1.z, u1.w};
#pragma unroll
    for (int u = 0; u < 8; ++u) {
      v[2 * u]     = bf2f(uu[u] & 0xffff);
      v[2 * u + 1] = bf2f(uu[u] >> 16);
    }
#pragma unroll
    for (int u = 0; u < 16; ++u) {
      const int j = j0 + u;
      if (j > i || j < np) v[u] = -3.0e38f;
      mx = fmaxf(mx, v[u]);
    }
  }
  mx = fmaxf(mx, __shfl_xor(mx, 32));
  mx = fmaxf(mx, __shfl_xor(mx, 16));
  mx = fmaxf(mx, __shfl_xor(mx, 8));
  mx = fmaxf(mx, __shfl_xor(mx, 4));
  mx = fmaxf(mx, __shfl_xor(mx, 2));
  mx = fmaxf(mx, __shfl_xor(mx, 1));
  if (lane == 0) red[w] = mx;
  __syncthreads();
  const float M = fmaxf(fmaxf(red[0], red[1]), fmaxf(red[2], red[3]));

  float sum = 0.f;
  if (act) {
#pragma unroll
    for (int u = 0; u < 16; ++u) {
      const float p = (v[u] > -1.0e30f) ? __expf(v[u] - M) : 0.f;
      v[u] = p;
      sum += p;
    }
  }
  sum += __shfl_xor(sum, 32);
  sum += __shfl_xor(sum, 16);
  sum += __shfl_xor(sum, 8);
  sum += __shfl_xor(sum, 4);
  sum += __shfl_xor(sum, 2);
  sum += __shfl_xor(sum, 1);
  if (lane == 0) red[4 + w] = sum;
  __syncthreads();
  const float inv = 1.0f / (red[4] + red[5] + red[6] + red[7]);

  if (act) {
    unsigned int o[8];
#pragma unroll
    for (int u = 0; u < 8; ++u) {
      const unsigned int lo = f2bf(v[2 * u] * inv);
      const unsigned int hi = f2bf(v[2 * u + 1] * inv);
      o[u] = lo | (hi << 16);
    }
    uint4 s0 = {o[0], o[1], o[2], o[3]};
    uint4 s1 = {o[4], o[5], o[6], o[7]};
    *(uint4*)(rowp + j0) = s0;
    *(uint4*)(rowp + j0 + 8) = s1;
  }
}

// ---------------------------------------------------------------------------
// zero_hi: zero out rows [2048, T) of out (atomic-accumulated region)
// ---------------------------------------------------------------------------
__global__ __launch_bounds__(256) void zero_hi(float* __restrict__ out) {
  const size_t i = ((size_t)blockIdx.x * 256 + threadIdx.x) * 4 +
                   (size_t)2048 * C_DIM;
  float4 z = {0.f, 0.f, 0.f, 0.f};
  *(float4*)(out + i) = z;
}

// ---------------------------------------------------------------------------
// padfix: rows < n_padd get uniform attention over ALL T keys (mean of V)
// ---------------------------------------------------------------------------
__global__ __launch_bounds__(256) void padfix(
    const unsigned short* __restrict__ vtb, const int* __restrict__ np_p,
    float* __restrict__ out, int T) {
  const int np = *np_p;
  const int row0 = blockIdx.x * 32;
  if (row0 >= np) return;
  const int pc = min(np - row0, 32);
  const int c4 = threadIdx.x << 2;
  float a[4] = {0.f, 0.f, 0.f, 0.f};
#pragma unroll
  for (int c = 0; c < 4; ++c) {
    const unsigned short* vr = vtb + (size_t)(c4 + c) * T;
    for (int j = 0; j < T; j += 8) {
      uint4 v = *(const uint4*)(vr + j);
      a[c] += bf2f(v.x & 0xffff) + bf2f(v.x >> 16) + bf2f(v.y & 0xffff) + bf2f(v.y >> 16)
            + bf2f(v.z & 0xffff) + bf2f(v.z >> 16) + bf2f(v.w & 0xffff) + bf2f(v.w >> 16);
    }
  }
  const float inv = 1.0f / (float)T;
  float4 rv = {a[0] * inv, a[1] * inv, a[2] * inv, a[3] * inv};
  for (int r = 0; r < pc; ++r)
    *(float4*)(out + (size_t)(row0 + r) * C_DIM + c4) = rv;
}

// ---------------------------------------------------------------------------
extern "C" void kernel_launch(void* const* d_in, const int* in_sizes, int n_in,
                              void* d_out, int out_size, void* d_ws, size_t ws_size,
                              hipStream_t stream) {
  const float* x    = (const float*)d_in[0];
  const float* W    = (const float*)d_in[1];
  const float* b    = (const float*)d_in[2];
  const int* n_padd = (const int*)d_in[3];
  float* out = (float*)d_out;

  const int T = in_sizes[0] / C_DIM;
  // ws layout (overlapping lifetimes):
  //   [0,16M)  qkb [T][2048] bf16   (Q|K, persistent until PV)
  //   [16,24M) vtb [1024][T] bf16   (V^T, persistent)
  //   [24M..)  phase1: xb [T][1024] (8M) + WT [3072][1024] (6M)
  //            phase2: P  [T][T] bf16 (33.5M) overlays xb/WT (written by
  //            S-GEMM strictly after the qkv GEMMs finish reading xb/WT)
  unsigned short* qkb = (unsigned short*)d_ws;
  unsigned short* vtb = qkb + (size_t)T * QKS;
  unsigned short* xb  = vtb + (size_t)C_DIM * T;
  unsigned short* WT  = xb  + (size_t)T * C_DIM;
  unsigned short* P   = xb;

  cast_x<<<(T * C_DIM) / 1024, 256, 0, stream>>>(x, xb);
  transpose_w<<<dim3(48, 16), 256, 0, stream>>>(W, WT);

  // Q|K = xb @ WT[0:2048]^T + b[col]
  gemm128<0><<<dim3(QKS / 128, T / 128), 256, 0, stream>>>(
      xb, WT, qkb, b, C_DIM, C_DIM, QKS, T);
  // V^T = WT[2048:3072] @ xb^T + b[2048+row]
  gemm128<1><<<dim3(T / 128, C_DIM / 128), 256, 0, stream>>>(
      WT + (size_t)QKS * C_DIM, xb, vtb, b + QKS, C_DIM, C_DIM, T, T);
  // S = Q @ K^T * 1/32  (lower-triangle tiles), bf16 [T][T]
  gemm128<2><<<dim3(T / 128, T / 128), 256, 0, stream>>>(
      qkb, qkb + C_DIM, P, b, QKS, QKS, T, T);
  // P = softmax(S) row-wise (normalized, masked)
  softmax_rows<<<T, 256, 0, stream>>>(P, n_padd, T);
  // zero atomic-target rows, then O = P @ V (causal K, split-K>=2048 atomic)
  zero_hi<<<((T - 2048) * C_DIM) / 1024, 256, 0, stream>>>(out);
  {
    const int nyt = T / 128;
    const int ex = nyt > 16 ? nyt - 16 : 0;
    gemm128<3><<<dim3(C_DIM / 128, nyt + ex), 256, 0, stream>>>(
        P, vtb, out, b, T, T, C_DIM, T);
  }
  padfix<<<T / 32, 256, 0, stream>>>(vtb, n_padd, out, T);
}